// Round 2
// baseline (831.249 us; speedup 1.0000x reference)
//
#include <hip/hip_runtime.h>

// H=256, N=131072, E=262144, M=1024
#define H_DIM 256
#define N_NODES 131072
#define E_EDGES 262144
#define M_SEGS 1024

typedef __attribute__((ext_vector_type(4))) float f32x4;
typedef __attribute__((ext_vector_type(8))) short bf16x8;
typedef __attribute__((ext_vector_type(2))) unsigned int u32x2;

__device__ inline unsigned short f2bf(float f) {
  union { float f; unsigned int u; } v; v.f = f;
  unsigned int r = v.u + 0x7FFFu + ((v.u >> 16) & 1u);  // RNE
  return (unsigned short)(r >> 16);
}
__device__ inline float bf2f(unsigned short u) {
  union { unsigned int i; float f; } v; v.i = ((unsigned int)u) << 16;
  return v.f;
}

// ---------------------------------------------------------------- K0: weights fp32->bf16
__global__ void convert_weights(const float* __restrict__ U, const float* __restrict__ A,
                                const float* __restrict__ V, const float* __restrict__ W,
                                unsigned short* __restrict__ dst) {
  int i = blockIdx.x * blockDim.x + threadIdx.x;   // 0..65535
  dst[i]          = f2bf(U[i]);
  dst[65536 + i]  = f2bf(A[i]);
  dst[131072 + i] = f2bf(V[i]);
  dst[196608 + i] = f2bf(W[i]);
}

// ---------------------------------------------------------------- K1: NV = node@V.T, NW = node@W.T  (bf16 out)
// D[h][node] = sum_k Wm[h][k]*node[node][k]; A-frag = weight rows, B-frag = node rows (LDS).
__global__ __launch_bounds__(512) void node_gemm(
    const float* __restrict__ node,
    const unsigned short* __restrict__ Vbf,
    const unsigned short* __restrict__ Wbf,
    unsigned short* __restrict__ NV,
    unsigned short* __restrict__ NW) {
  __shared__ unsigned short tile[128 * 256];  // 64 KiB, XOR-swizzled rows
  const int tid = threadIdx.x;
  const long nbase = (long)blockIdx.x * 128;

  // stage 128x256 fp32 -> bf16 LDS (swizzled: byte ^= (row&7)<<4)
  #pragma unroll
  for (int i = 0; i < 16; ++i) {
    int c = tid + i * 512;          // 0..8191
    int row = c >> 6;
    int ch = c & 63;                // float4 chunk within row
    f32x4 v = *reinterpret_cast<const f32x4*>(node + (nbase + row) * 256 + ch * 4);
    union { unsigned short u[4]; u32x2 d; } p;
    p.u[0] = f2bf(v.x); p.u[1] = f2bf(v.y); p.u[2] = f2bf(v.z); p.u[3] = f2bf(v.w);
    int byte = (row * 512 + ch * 8) ^ ((row & 7) << 4);
    *reinterpret_cast<u32x2*>(reinterpret_cast<char*>(tile) + byte) = p.d;
  }
  __syncthreads();

  const int lane = tid & 63;
  const int wid = tid >> 6;
  const int hg = wid >> 1;     // 0..3  -> h base hg*64
  const int ng = wid & 1;      // 0..1  -> node base ng*64
  const int l15 = lane & 15;
  const int l4 = lane >> 4;

  // two passes (V then W) to keep acc at 64 VGPR
  for (int pass = 0; pass < 2; ++pass) {
    const unsigned short* Wm = pass ? Wbf : Vbf;
    unsigned short* Out = pass ? NW : NV;
    f32x4 acc[4][4];
    #pragma unroll
    for (int a = 0; a < 4; ++a)
      #pragma unroll
      for (int b = 0; b < 4; ++b) acc[a][b] = f32x4{0.f, 0.f, 0.f, 0.f};

    for (int k0 = 0; k0 < 8; ++k0) {
      const int ku = k0 * 32 + l4 * 8;   // ushort offset within a 256-wide row
      bf16x8 av[4], bn[4];
      #pragma unroll
      for (int hm = 0; hm < 4; ++hm) {
        int hr = hg * 64 + hm * 16 + l15;
        av[hm] = *reinterpret_cast<const bf16x8*>(Wm + hr * 256 + ku);
      }
      #pragma unroll
      for (int nn = 0; nn < 4; ++nn) {
        int nr = ng * 64 + nn * 16 + l15;
        int byte = (nr * 512 + ku * 2) ^ ((nr & 7) << 4);
        bn[nn] = *reinterpret_cast<const bf16x8*>(reinterpret_cast<const char*>(tile) + byte);
      }
      #pragma unroll
      for (int hm = 0; hm < 4; ++hm)
        #pragma unroll
        for (int nn = 0; nn < 4; ++nn)
          acc[hm][nn] = __builtin_amdgcn_mfma_f32_16x16x32_bf16(av[hm], bn[nn], acc[hm][nn], 0, 0, 0);
    }
    // store: lane holds h = hg*64+hm*16+l4*4+j (j consecutive) at node = nbase+ng*64+nn*16+l15
    #pragma unroll
    for (int hm = 0; hm < 4; ++hm)
      #pragma unroll
      for (int nn = 0; nn < 4; ++nn) {
        long nd = nbase + ng * 64 + nn * 16 + l15;
        int h0 = hg * 64 + hm * 16 + l4 * 4;
        union { unsigned short u[4]; u32x2 d; } p;
        #pragma unroll
        for (int j = 0; j < 4; ++j) p.u[j] = f2bf(acc[hm][nn][j]);
        *reinterpret_cast<u32x2*>(Out + nd * 256 + h0) = p.d;
      }
  }
}

// ---------------------------------------------------------------- K2: fused edge GEMMs + gather-add + gate + segment-sum
__global__ __launch_bounds__(512) void edge_kernel(
    const float* __restrict__ edge_feats,
    const unsigned short* __restrict__ Ubf,
    const unsigned short* __restrict__ Abf,
    const unsigned short* __restrict__ NV,
    const unsigned short* __restrict__ NW,
    const int* __restrict__ eidx,
    const int* __restrict__ segids,
    const float* __restrict__ U_b, const float* __restrict__ V_b,
    const float* __restrict__ W_b, const float* __restrict__ A_b,
    float* __restrict__ out) {
  __shared__ unsigned short etile[64 * 256];  // 32 KiB, swizzled
  __shared__ float gsum[64 * 256];            // 64 KiB (later reused as gated output)
  __shared__ int sseg[64];
  const int tid = threadIdx.x;
  const long ebase = (long)blockIdx.x * 64;

  // stage edge tile fp32 -> bf16 LDS (swizzled)
  #pragma unroll
  for (int i = 0; i < 8; ++i) {
    int c = tid + i * 512;          // 0..4095
    int row = c >> 6;
    int ch = c & 63;
    f32x4 v = *reinterpret_cast<const f32x4*>(edge_feats + (ebase + row) * 256 + ch * 4);
    union { unsigned short u[4]; u32x2 d; } p;
    p.u[0] = f2bf(v.x); p.u[1] = f2bf(v.y); p.u[2] = f2bf(v.z); p.u[3] = f2bf(v.w);
    int byte = (row * 512 + ch * 8) ^ ((row & 7) << 4);
    *reinterpret_cast<u32x2*>(reinterpret_cast<char*>(etile) + byte) = p.d;
  }
  // stage gathered NV[x]+NW[y] (fp32, linear layout)
  {
    int row = tid >> 3;             // 0..63
    int sub = tid & 7;
    int n0 = eidx[(ebase + row) * 2 + 0];
    int n1 = eidx[(ebase + row) * 2 + 1];
    const unsigned short* pv = NV + (long)n0 * 256;
    const unsigned short* pw = NW + (long)n1 * 256;
    #pragma unroll
    for (int q = 0; q < 4; ++q) {
      int c0 = q * 64 + sub * 8;
      bf16x8 a = *reinterpret_cast<const bf16x8*>(pv + c0);
      bf16x8 b = *reinterpret_cast<const bf16x8*>(pw + c0);
      float r[8];
      #pragma unroll
      for (int e = 0; e < 8; ++e)
        r[e] = bf2f((unsigned short)a[e]) + bf2f((unsigned short)b[e]);
      f32x4 lo = {r[0], r[1], r[2], r[3]};
      f32x4 hi = {r[4], r[5], r[6], r[7]};
      *reinterpret_cast<f32x4*>(&gsum[row * 256 + c0]) = lo;
      *reinterpret_cast<f32x4*>(&gsum[row * 256 + c0 + 4]) = hi;
    }
  }
  if (tid < 64) sseg[tid] = segids[ebase + tid];
  __syncthreads();

  const int lane = tid & 63;
  const int wid = tid >> 6;
  const int wr = wid >> 2;   // 0..1: edge-row base wr*32
  const int wc = wid & 3;    // 0..3: h base wc*64
  const int l15 = lane & 15;
  const int l4 = lane >> 4;

  f32x4 aS[2][4], aA[2][4];
  #pragma unroll
  for (int m = 0; m < 2; ++m)
    #pragma unroll
    for (int n = 0; n < 4; ++n) {
      aS[m][n] = f32x4{0.f, 0.f, 0.f, 0.f};
      aA[m][n] = f32x4{0.f, 0.f, 0.f, 0.f};
    }

  for (int k0 = 0; k0 < 8; ++k0) {
    const int ku = k0 * 32 + l4 * 8;
    bf16x8 a[2];
    #pragma unroll
    for (int m = 0; m < 2; ++m) {
      int row = wr * 32 + m * 16 + l15;
      int byte = (row * 512 + ku * 2) ^ ((row & 7) << 4);
      a[m] = *reinterpret_cast<const bf16x8*>(reinterpret_cast<const char*>(etile) + byte);
    }
    bf16x8 bu[4], ba[4];
    #pragma unroll
    for (int n = 0; n < 4; ++n) {
      int hr = wc * 64 + n * 16 + l15;
      bu[n] = *reinterpret_cast<const bf16x8*>(Ubf + hr * 256 + ku);
      ba[n] = *reinterpret_cast<const bf16x8*>(Abf + hr * 256 + ku);
    }
    #pragma unroll
    for (int m = 0; m < 2; ++m)
      #pragma unroll
      for (int n = 0; n < 4; ++n) {
        aS[m][n] = __builtin_amdgcn_mfma_f32_16x16x32_bf16(a[m], bu[n], aS[m][n], 0, 0, 0);
        aA[m][n] = __builtin_amdgcn_mfma_f32_16x16x32_bf16(a[m], ba[n], aA[m][n], 0, 0, 0);
      }
  }

  // finalize: syn = accS + gsum + (U_b+V_b+W_b); gated = sigmoid(syn)*(accA + A_b); overwrite gsum
  #pragma unroll
  for (int n = 0; n < 4; ++n) {
    int h = wc * 64 + n * 16 + l15;
    float bs = U_b[h] + V_b[h] + W_b[h];
    float ba_ = A_b[h];
    #pragma unroll
    for (int m = 0; m < 2; ++m)
      #pragma unroll
      for (int j = 0; j < 4; ++j) {
        int row = wr * 32 + m * 16 + l4 * 4 + j;
        float syn = aS[m][n][j] + gsum[row * 256 + h] + bs;
        float gate = 1.f / (1.f + __expf(-syn));
        float gv = gate * (aA[m][n][j] + ba_);
        gsum[row * 256 + h] = gv;
      }
  }
  __syncthreads();

  // segment reduction: thread owns one column over 32 rows; run-length flush (segids sorted)
  {
    int col = tid & 255;
    int r0 = (tid >> 8) * 32;
    float acc = 0.f;
    int cur = sseg[r0];
    for (int r = r0; r < r0 + 32; ++r) {
      int s = sseg[r];
      if (s != cur) {
        atomicAdd(&out[(long)cur * 256 + col], acc);
        acc = 0.f;
        cur = s;
      }
      acc += gsum[r * 256 + col];
    }
    atomicAdd(&out[(long)cur * 256 + col], acc);
  }
}

// ---------------------------------------------------------------- launch
extern "C" void kernel_launch(void* const* d_in, const int* in_sizes, int n_in,
                              void* d_out, int out_size, void* d_ws, size_t ws_size,
                              hipStream_t stream) {
  const float* node_feats = (const float*)d_in[0];
  const float* edge_feats = (const float*)d_in[1];
  const float* U_w = (const float*)d_in[2];
  const float* U_b = (const float*)d_in[3];
  const float* V_w = (const float*)d_in[4];
  const float* V_b = (const float*)d_in[5];
  const float* W_w = (const float*)d_in[6];
  const float* W_b = (const float*)d_in[7];
  const float* A_w = (const float*)d_in[8];
  const float* A_b = (const float*)d_in[9];
  const int* eidx = (const int*)d_in[10];
  const int* segids = (const int*)d_in[11];

  unsigned short* ws = (unsigned short*)d_ws;
  unsigned short* Ubf = ws;                 // 65536
  unsigned short* Abf = ws + 65536;
  unsigned short* Vbf = ws + 131072;
  unsigned short* Wbf = ws + 196608;
  unsigned short* NV = ws + 262144;                     // N*256 bf16
  unsigned short* NW = NV + (long)N_NODES * 256;        // N*256 bf16

  hipMemsetAsync(d_out, 0, (size_t)out_size * sizeof(float), stream);
  convert_weights<<<256, 256, 0, stream>>>(U_w, A_w, V_w, W_w, ws);
  node_gemm<<<N_NODES / 128, 512, 0, stream>>>(node_feats, Vbf, Wbf, NV, NW);
  edge_kernel<<<E_EDGES / 64, 512, 0, stream>>>(edge_feats, Ubf, Abf, NV, NW,
                                                eidx, segids, U_b, V_b, W_b, A_b,
                                                (float*)d_out);
}